// Round 4
// baseline (203.456 us; speedup 1.0000x reference)
//
#include <hip/hip_runtime.h>

constexpr int Bn = 8192;   // batch
constexpr int Dn = 512;    // feature dim
constexpr int ROWS_PER_BLOCK = 4;   // one row per wave
#define EPSF 1e-7f
#define MARGINF 1.0f
#define FPSCALE 16777216.0  // 2^24 fixed-point for deterministic mean

__device__ __forceinline__ void amax_combine(float& bv, int& bi, float v, int i) {
    // argmax with first-index tie-break (matches jnp.argmax)
    if (v > bv || (v == bv && i < bi)) { bv = v; bi = i; }
}

// ws layout: [0] unsigned long long fixed-point sum, [1] unsigned done-counter
__global__ __launch_bounds__(256) void triplet_fused(
    const float* __restrict__ feats,
    const int*   __restrict__ labels,
    const float* __restrict__ noise,
    unsigned long long* __restrict__ ws,
    float*       __restrict__ out)
{
    __shared__ unsigned slab_u[Bn / 4];   // 8 KB packed label bytes
    __shared__ int s_any;
    __shared__ unsigned long long s_q[ROWS_PER_BLOCK];

    const int tid  = threadIdx.x;
    const int lane = tid & 63;
    const int wv   = tid >> 6;

    // ---- label dtype detect (int64 => odd int32 words all zero) ----
    if (tid == 0) s_any = 0;
    __syncthreads();
    if (tid < 128 && labels[2 * tid + 1] != 0) atomicOr(&s_any, 1);
    __syncthreads();
    const bool is64 = (s_any == 0);

    // ---- pack labels into LDS as bytes (L2-hot source) ----
    if (is64) {
        const long long* l8 = (const long long*)labels;
        for (int w = tid; w < Bn / 4; w += 256) {
            unsigned b0 = (unsigned)l8[w * 4 + 0] & 0xffu;
            unsigned b1 = (unsigned)l8[w * 4 + 1] & 0xffu;
            unsigned b2 = (unsigned)l8[w * 4 + 2] & 0xffu;
            unsigned b3 = (unsigned)l8[w * 4 + 3] & 0xffu;
            slab_u[w] = b0 | (b1 << 8) | (b2 << 16) | (b3 << 24);
        }
    } else {
        for (int w = tid; w < Bn / 4; w += 256) {
            int4 v = ((const int4*)labels)[w];
            slab_u[w] = ((unsigned)v.x & 0xffu) | (((unsigned)v.y & 0xffu) << 8) |
                        (((unsigned)v.z & 0xffu) << 16) | (((unsigned)v.w & 0xffu) << 24);
        }
    }
    __syncthreads();

    // ================= per-wave: one anchor row, no block syncs =================
    const int row = blockIdx.x * ROWS_PER_BLOCK + wv;
    const unsigned myLab = (slab_u[row >> 2] >> ((row & 3) * 8)) & 0xffu;

    const float* __restrict__ n0 = noise + (size_t)row * Bn;
    const float* __restrict__ n1 = noise + (size_t)Bn * Bn + (size_t)row * Bn;

    // 4 independent slot-accumulators break the dependent compare chain.
    float pbv[4] = {-1.0f, -1.0f, -1.0f, -1.0f};
    float nbv[4] = {-1.0f, -1.0f, -1.0f, -1.0f};
    int   pbi[4] = {0x7FFFFFFF, 0x7FFFFFFF, 0x7FFFFFFF, 0x7FFFFFFF};
    int   nbi[4] = {0x7FFFFFFF, 0x7FFFFFFF, 0x7FFFFFFF, 0x7FFFFFFF};

#pragma unroll 2
    for (int j = lane * 4; j < Bn; j += 256) {   // 32 iters/wave, 1 KB/wave/iter/stream
        float4 v0 = *(const float4*)(n0 + j);
        float4 v1 = *(const float4*)(n1 + j);
        unsigned lw = slab_u[j >> 2];
        const float* f0 = (const float*)&v0;
        const float* f1 = (const float*)&v1;
#pragma unroll
        for (int k = 0; k < 4; ++k) {
            unsigned lk = (lw >> (k * 8)) & 0xffu;
            // within a slot indices strictly increase -> strictly-greater keeps first max
            float cp = (lk == myLab) ? f0[k] : -1.0f;
            if (cp > pbv[k]) { pbv[k] = cp; pbi[k] = j + k; }
            float cn = (lk != myLab) ? f1[k] : -1.0f;
            if (cn > nbv[k]) { nbv[k] = cn; nbi[k] = j + k; }
        }
    }

    // merge slots (equal values: lower slot = lower index)
    float pv = pbv[0]; int pi_ = pbi[0];
    float nv = nbv[0]; int ni_ = nbi[0];
#pragma unroll
    for (int k = 1; k < 4; ++k) {
        amax_combine(pv, pi_, pbv[k], pbi[k]);
        amax_combine(nv, ni_, nbv[k], nbi[k]);
    }

    // wave-level argmax reduce (shuffle only, no LDS, no syncthreads)
    for (int off = 32; off; off >>= 1) {
        float ov = __shfl_down(pv, off, 64);
        int   oi = __shfl_down(pi_, off, 64);
        amax_combine(pv, pi_, ov, oi);
        ov = __shfl_down(nv, off, 64);
        oi = __shfl_down(ni_, off, 64);
        amax_combine(nv, ni_, ov, oi);
    }
    // broadcast winners to all 64 lanes
    const int   pi  = __shfl(pi_, 0, 64);
    int         ni  = __shfl(ni_, 0, 64);
    const float nvb = __shfl(nv, 0, 64);
    if (nvb < 0.0f) ni = row;   // has_neg fallback -> anchor

    // ---- triplet distances: two contiguous 1 KB chunks per row ----
    const float* fa = feats + (size_t)row * Dn;
    const float* fp = feats + (size_t)pi  * Dn;
    const float* fn = feats + (size_t)ni  * Dn;
    float dap = 0.0f, dan = 0.0f;
#pragma unroll
    for (int c = 0; c < 2; ++c) {
        const int o = c * 256 + lane * 4;
        float4 a = *(const float4*)(fa + o);
        float4 p = *(const float4*)(fp + o);
        float4 q = *(const float4*)(fn + o);
        float d;
        d = a.x - p.x + EPSF; dap += d * d;
        d = a.y - p.y + EPSF; dap += d * d;
        d = a.z - p.z + EPSF; dap += d * d;
        d = a.w - p.w + EPSF; dap += d * d;
        d = a.x - q.x + EPSF; dan += d * d;
        d = a.y - q.y + EPSF; dan += d * d;
        d = a.z - q.z + EPSF; dan += d * d;
        d = a.w - q.w + EPSF; dan += d * d;
    }
    for (int off = 32; off; off >>= 1) {
        dap += __shfl_down(dap, off, 64);
        dan += __shfl_down(dan, off, 64);
    }
    if (lane == 0) {
        float loss = fmaxf(sqrtf(dap) - sqrtf(dan) + MARGINF, 0.0f);
        s_q[wv] = (unsigned long long)llrint((double)loss * FPSCALE);
    }
    __syncthreads();

    // ---- one global atomic per block; last block writes the mean ----
    if (tid == 0) {
        unsigned long long q = s_q[0] + s_q[1] + s_q[2] + s_q[3];
        atomicAdd(ws, q);
        __threadfence();
        unsigned done = atomicAdd((unsigned*)(ws + 1), 1u);
        if (done == gridDim.x - 1) {
            __threadfence();
            unsigned long long s = atomicAdd(ws, 0ULL);   // device-scope read
            out[0] = (float)((double)s / FPSCALE / (double)Bn);
        }
    }
}

extern "C" void kernel_launch(void* const* d_in, const int* in_sizes, int n_in,
                              void* d_out, int out_size, void* d_ws, size_t ws_size,
                              hipStream_t stream) {
    const float* feats  = (const float*)d_in[0];
    const int*   labels = (const int*)d_in[1];
    const float* noise  = (const float*)d_in[2];

    hipMemsetAsync(d_ws, 0, 16, stream);   // stream-ordered, graph-capture legal
    triplet_fused<<<Bn / ROWS_PER_BLOCK, 256, 0, stream>>>(
        feats, labels, noise, (unsigned long long*)d_ws, (float*)d_out);
}